// Round 2
// 971.564 us; speedup vs baseline: 1.0869x; 1.0869x over previous
//
#include <hip/hip_runtime.h>

// Multiscale Residual VQ (VAR-style), MI355X gfx950.
// Round 7 = Round 6 + container-failure defenses:
//   - static LDS capped at exactly 64KB: packs/idxs alias the smem staging
//     buffer (packs only live after the final barrier; idxs consumed into
//     registers before first STAGE, guarded by an extra barrier),
//   - smem aligned(16) (global_load_lds writes base+lane*16),
// Round 6 core (unchanged):
//   (a) global_load_lds width=16 direct-to-LDS staging (no VGPR round trip,
//       no ds_write bank conflicts - round 5's 1.68e7 SQ_LDS_BANK_CONFLICT),
//   (b) unpadded [128][32]-half tiles, pre-swizzled global source:
//       16B slot p ^ ((row>>1)&3); involution applied again on read =>
//       bit-identical operands, same MFMA order => no argmin-flip risk,
//   (c) 2-phase pipeline: double-buffered LDS, STAGE(next) issued before
//       ds_read+MFMA(cur), ONE barrier per K-step.
// k_conv / k_combine / pre-pass kernels unchanged from round 5.

#define ND 512
#define NCB 4096

typedef _Float16 half8v __attribute__((ext_vector_type(8)));
typedef float floatx4 __attribute__((ext_vector_type(4)));

struct HL { _Float16 h, l; };

__device__ __forceinline__ HL split2(float v) {
    HL r;
    r.h = (_Float16)v;
    r.l = (_Float16)((v - (float)r.h) * 4096.0f);
    return r;
}

__device__ __forceinline__ unsigned long long pack_dist(float d, int n) {
    unsigned u = __float_as_uint(d);
    u = (u & 0x80000000u) ? ~u : (u | 0x80000000u);   // monotone total order
    return ((unsigned long long)u << 32) | (unsigned)n; // tie -> lowest idx
}

// async global->LDS, 16B per lane; LDS dest = wave-uniform base + lane*16
__device__ __forceinline__ void gl2lds16(const _Float16* g, _Float16* l) {
    __builtin_amdgcn_global_load_lds(
        (const __attribute__((address_space(1))) unsigned int*)g,
        (__attribute__((address_space(3))) unsigned int*)l, 16, 0, 0);
}

// e_sq[c] = sum_d embed[c,d]^2, fp64 accumulate
__global__ __launch_bounds__(256) void k_esq(const float* __restrict__ embed,
                                             float* __restrict__ esq) {
    int c = blockIdx.x * 4 + (threadIdx.x >> 6);
    int lane = threadIdx.x & 63;
    const float* row = embed + (size_t)c * ND;
    double acc = 0.0;
#pragma unroll
    for (int i = 0; i < ND / 64; ++i) {
        float v = row[lane + i * 64];
        acc += (double)v * (double)v;
    }
#pragma unroll
    for (int off = 32; off > 0; off >>= 1) acc += __shfl_down(acc, off, 64);
    if (lane == 0) esq[c] = (float)acc;
}

__global__ __launch_bounds__(256) void k_copy(const float* __restrict__ src,
                                              float* __restrict__ dst) {
    int gid = blockIdx.x * 256 + threadIdx.x;
    ((float4*)dst)[gid] = ((const float4*)src)[gid];
}

// embed -> ehi/elo (4096x512 halves)
__global__ __launch_bounds__(256) void k_split_embed(const float* __restrict__ embed,
        _Float16* __restrict__ eh, _Float16* __restrict__ el) {
    int gid = blockIdx.x * 256 + threadIdx.x;       // 524288 float4s
    float4 v = ((const float4*)embed)[gid];
    HL a = split2(v.x), b = split2(v.y), c = split2(v.z), d = split2(v.w);
    _Float16* ph = eh + (size_t)gid * 4;
    _Float16* pl = el + (size_t)gid * 4;
    ph[0] = a.h; ph[1] = b.h; ph[2] = c.h; ph[3] = d.h;
    pl[0] = a.l; pl[1] = b.l; pl[2] = c.l; pl[3] = d.l;
}

// Wt2[kp][tap*512+dout][din] hi/lo from pw[kp][dout][din][tap]; output-indexed
__global__ __launch_bounds__(256) void k_split_w(const float* __restrict__ pw,
        _Float16* __restrict__ wh, _Float16* __restrict__ wl) {
    int gid = blockIdx.x * 256 + threadIdx.x;       // 4*1536*512 = 3,145,728
    int din = gid & 511;
    int nn = (gid >> 9) % 1536;
    int kp = gid / (512 * 1536);
    int tap = nn >> 9;
    int dout = nn & 511;
    float v = pw[(((size_t)(kp * 512 + dout) * 512) + din) * 3 + tap];
    HL r = split2(v);
    wh[gid] = r.h;
    wl[gid] = r.l;
}

// z[b,j,d] = block mean of residual (fp64 acc) -> split halves zh/zl
__global__ __launch_bounds__(256) void k_zmean(const float* __restrict__ resid,
        _Float16* __restrict__ zh, _Float16* __restrict__ zl, int s, int lg) {
    int gid = blockIdx.x * 256 + threadIdx.x;       // 16*s*512 threads
    int d = gid & 511;
    int j = (gid >> 9) & (s - 1);
    int b = gid >> (9 + lg);
    int r = 512 >> lg;
    const float* p = resid + ((size_t)((b << 9) + (j << (9 - lg))) << 9) + d;
    double acc = 0.0;
#pragma unroll 4
    for (int m = 0; m < r; ++m) acc += (double)p[(size_t)m * ND];
    float v = (float)(acc * (1.0 / (double)r));
    HL hl = split2(v);
    zh[gid] = hl.h;
    zl[gid] = hl.l;
}

// ---------------- dist: block 128m x 128n, 4 waves (2x2) each 64x64 ----------------
// global_load_lds staging into [2][4][128][32] halves, swizzled source, 2-phase.
__global__ __launch_bounds__(256, 2) void k_dist_mfma(const _Float16* __restrict__ zh,
        const _Float16* __restrict__ zl, const _Float16* __restrict__ eh,
        const _Float16* __restrict__ el, const float* __restrict__ esq,
        unsigned long long* __restrict__ minbuf, int M) {
    __shared__ _Float16 smem[2][4][4096] __attribute__((aligned(16)));  // 64KB exactly
    // packs aliases smem: only live after the main loop's final barrier
    unsigned long long (*packs)[2] = reinterpret_cast<unsigned long long(*)[2]>(&smem[0][0][0]);
    int tid = threadIdx.x;
    int lane = tid & 63, wave = tid >> 6;
    int wm = wave >> 1, wn = wave & 1;
    int quad = lane >> 4, l15 = lane & 15;
    int m0 = blockIdx.x * 128, n0 = blockIdx.y * 128;

    // ---- staging geometry: lane covers (row, 16B-slot) for j=0 and j=1 blocks
    int slot = lane & 3;
    int r0 = wave * 32 + (lane >> 2);
    int r1 = r0 + 16;
    int sc0 = (slot ^ ((r0 >> 1) & 3)) << 3;    // swizzled source col (halves)
    int sc1 = (slot ^ ((r1 >> 1) & 3)) << 3;
    int a0 = m0 + r0; if (a0 >= M) a0 = M - 1;
    int a1 = m0 + r1; if (a1 >= M) a1 = M - 1;
    const _Float16* gA0h = zh + (size_t)a0 * 512 + sc0;
    const _Float16* gA1h = zh + (size_t)a1 * 512 + sc1;
    const _Float16* gA0l = zl + (size_t)a0 * 512 + sc0;
    const _Float16* gA1l = zl + (size_t)a1 * 512 + sc1;
    const _Float16* gB0h = eh + (size_t)(n0 + r0) * 512 + sc0;
    const _Float16* gB1h = eh + (size_t)(n0 + r1) * 512 + sc1;
    const _Float16* gB0l = el + (size_t)(n0 + r0) * 512 + sc0;
    const _Float16* gB1l = el + (size_t)(n0 + r1) * 512 + sc1;
    int ld0 = wave * 1024;          // (wave*32 rows)*32 halves, wave-uniform dest
    int ld1 = ld0 + 512;            // +16 rows

    // ---- fragment read geometry (un-swizzle on read; bit-identical data)
    int cslot = (quad ^ ((l15 >> 1) & 3)) << 3;
    int rbA = (wm * 64 + l15) * 32 + cslot;
    int rbB = (wn * 64 + l15) * 32 + cslot;

#define STAGE_D(buf, kb) do { \
    gl2lds16(gA0h + (kb), &smem[buf][0][ld0]); \
    gl2lds16(gA1h + (kb), &smem[buf][0][ld1]); \
    gl2lds16(gA0l + (kb), &smem[buf][1][ld0]); \
    gl2lds16(gA1l + (kb), &smem[buf][1][ld1]); \
    gl2lds16(gB0h + (kb), &smem[buf][2][ld0]); \
    gl2lds16(gB1h + (kb), &smem[buf][2][ld1]); \
    gl2lds16(gB0l + (kb), &smem[buf][3][ld0]); \
    gl2lds16(gB1l + (kb), &smem[buf][3][ld1]); \
} while (0)

    floatx4 acch[4][4], accx[4][4];
#pragma unroll
    for (int i = 0; i < 4; ++i)
#pragma unroll
        for (int j = 0; j < 4; ++j)
#pragma unroll
            for (int r = 0; r < 4; ++r) { acch[i][j][r] = 0.f; accx[i][j][r] = 0.f; }

    STAGE_D(0, 0);
    __syncthreads();
    int cur = 0;
    for (int it = 0; it < 16; ++it) {
        if (it < 15) STAGE_D(cur ^ 1, (it + 1) * 32);
        const _Float16* sAh = &smem[cur][0][0];
        const _Float16* sAl = &smem[cur][1][0];
        const _Float16* sBh = &smem[cur][2][0];
        const _Float16* sBl = &smem[cur][3][0];
        half8v afh[4], afl[4], bfh[4], bfl[4];
#pragma unroll
        for (int tm = 0; tm < 4; ++tm) {
            afh[tm] = *(const half8v*)&sAh[rbA + tm * 512];
            afl[tm] = *(const half8v*)&sAl[rbA + tm * 512];
        }
#pragma unroll
        for (int tn = 0; tn < 4; ++tn) {
            bfh[tn] = *(const half8v*)&sBh[rbB + tn * 512];
            bfl[tn] = *(const half8v*)&sBl[rbB + tn * 512];
        }
#pragma unroll
        for (int tm = 0; tm < 4; ++tm)
#pragma unroll
            for (int tn = 0; tn < 4; ++tn) {
                acch[tm][tn] = __builtin_amdgcn_mfma_f32_16x16x32_f16(afh[tm], bfh[tn], acch[tm][tn], 0, 0, 0);
                accx[tm][tn] = __builtin_amdgcn_mfma_f32_16x16x32_f16(afh[tm], bfl[tn], accx[tm][tn], 0, 0, 0);
                accx[tm][tn] = __builtin_amdgcn_mfma_f32_16x16x32_f16(afl[tm], bfh[tn], accx[tm][tn], 0, 0, 0);
            }
        __syncthreads();
        cur ^= 1;
    }
#undef STAGE_D
    float es[4];
#pragma unroll
    for (int tn = 0; tn < 4; ++tn) es[tn] = esq[n0 + wn * 64 + tn * 16 + l15];
#pragma unroll
    for (int tm = 0; tm < 4; ++tm)
#pragma unroll
        for (int reg = 0; reg < 4; ++reg) {
            unsigned long long best = ~0ull;
#pragma unroll
            for (int tn = 0; tn < 4; ++tn) {
                float dot = acch[tm][tn][reg] + accx[tm][tn][reg] * (1.0f / 4096.0f);
                int n = n0 + wn * 64 + tn * 16 + l15;
                float dd = fmaf(-2.f, dot, es[tn]);
                unsigned long long p = pack_dist(dd, n);
                best = p < best ? p : best;
            }
#pragma unroll
            for (int off = 1; off < 16; off <<= 1) {
                unsigned long long q = __shfl_xor(best, off, 64);
                best = q < best ? q : best;
            }
            if (l15 == 0) packs[wm * 64 + tm * 16 + quad * 4 + reg][wn] = best;
        }
    __syncthreads();
    if (tid < 128 && m0 + tid < M) {
        unsigned long long b0 = packs[tid][0], b1 = packs[tid][1];
        atomicMin(&minbuf[m0 + tid], b0 < b1 ? b0 : b1);
    }
}

// ---------------- phi: u[m][tap*512+dout] = (W_tap q_m)[dout], m = b*s+j ----------------
// GEMM [M x 512] x [512 x 1536]; A rows gathered from pre-split embed by idx.
// Same global_load_lds + swizzle + 2-phase structure as k_dist_mfma.
__global__ __launch_bounds__(256, 2) void k_phi(const _Float16* __restrict__ eh,
        const _Float16* __restrict__ el, const _Float16* __restrict__ wh,
        const _Float16* __restrict__ wl, const unsigned long long* __restrict__ minbuf,
        float* __restrict__ u, int M) {
    __shared__ _Float16 smem[2][4][4096] __attribute__((aligned(16)));  // 64KB exactly
    // idxs aliases smem: consumed into registers before the first STAGE
    int* idxs = reinterpret_cast<int*>(&smem[0][0][0]);
    int tid = threadIdx.x;
    int lane = tid & 63, wave = tid >> 6;
    int wm = wave >> 1, wn = wave & 1;
    int quad = lane >> 4, l15 = lane & 15;
    int m0 = blockIdx.x * 128, n0 = blockIdx.y * 128;
    if (tid < 128) {
        int m = m0 + tid; if (m >= M) m = M - 1;
        idxs[tid] = (int)(unsigned)minbuf[m];
    }
    __syncthreads();

    int slot = lane & 3;
    int r0 = wave * 32 + (lane >> 2);
    int r1 = r0 + 16;
    int sc0 = (slot ^ ((r0 >> 1) & 3)) << 3;
    int sc1 = (slot ^ ((r1 >> 1) & 3)) << 3;
    int code0 = idxs[r0];
    int code1 = idxs[r1];
    __syncthreads();   // all waves done reading idxs before DMA overwrites smem
    const _Float16* gA0h = eh + (size_t)code0 * 512 + sc0;
    const _Float16* gA1h = eh + (size_t)code1 * 512 + sc1;
    const _Float16* gA0l = el + (size_t)code0 * 512 + sc0;
    const _Float16* gA1l = el + (size_t)code1 * 512 + sc1;
    const _Float16* gB0h = wh + (size_t)(n0 + r0) * 512 + sc0;
    const _Float16* gB1h = wh + (size_t)(n0 + r1) * 512 + sc1;
    const _Float16* gB0l = wl + (size_t)(n0 + r0) * 512 + sc0;
    const _Float16* gB1l = wl + (size_t)(n0 + r1) * 512 + sc1;
    int ld0 = wave * 1024;
    int ld1 = ld0 + 512;

    int cslot = (quad ^ ((l15 >> 1) & 3)) << 3;
    int rbA = (wm * 64 + l15) * 32 + cslot;
    int rbB = (wn * 64 + l15) * 32 + cslot;

#define STAGE_P(buf, kb) do { \
    gl2lds16(gA0h + (kb), &smem[buf][0][ld0]); \
    gl2lds16(gA1h + (kb), &smem[buf][0][ld1]); \
    gl2lds16(gA0l + (kb), &smem[buf][1][ld0]); \
    gl2lds16(gA1l + (kb), &smem[buf][1][ld1]); \
    gl2lds16(gB0h + (kb), &smem[buf][2][ld0]); \
    gl2lds16(gB1h + (kb), &smem[buf][2][ld1]); \
    gl2lds16(gB0l + (kb), &smem[buf][3][ld0]); \
    gl2lds16(gB1l + (kb), &smem[buf][3][ld1]); \
} while (0)

    floatx4 acch[4][4], accx[4][4];
#pragma unroll
    for (int i = 0; i < 4; ++i)
#pragma unroll
        for (int j = 0; j < 4; ++j)
#pragma unroll
            for (int r = 0; r < 4; ++r) { acch[i][j][r] = 0.f; accx[i][j][r] = 0.f; }

    STAGE_P(0, 0);
    __syncthreads();
    int cur = 0;
    for (int it = 0; it < 16; ++it) {
        if (it < 15) STAGE_P(cur ^ 1, (it + 1) * 32);
        const _Float16* sAh = &smem[cur][0][0];
        const _Float16* sAl = &smem[cur][1][0];
        const _Float16* sBh = &smem[cur][2][0];
        const _Float16* sBl = &smem[cur][3][0];
        half8v afh[4], afl[4], bfh[4], bfl[4];
#pragma unroll
        for (int tm = 0; tm < 4; ++tm) {
            afh[tm] = *(const half8v*)&sAh[rbA + tm * 512];
            afl[tm] = *(const half8v*)&sAl[rbA + tm * 512];
        }
#pragma unroll
        for (int tn = 0; tn < 4; ++tn) {
            bfh[tn] = *(const half8v*)&sBh[rbB + tn * 512];
            bfl[tn] = *(const half8v*)&sBl[rbB + tn * 512];
        }
#pragma unroll
        for (int tm = 0; tm < 4; ++tm)
#pragma unroll
            for (int tn = 0; tn < 4; ++tn) {
                acch[tm][tn] = __builtin_amdgcn_mfma_f32_16x16x32_f16(afh[tm], bfh[tn], acch[tm][tn], 0, 0, 0);
                accx[tm][tn] = __builtin_amdgcn_mfma_f32_16x16x32_f16(afh[tm], bfl[tn], accx[tm][tn], 0, 0, 0);
                accx[tm][tn] = __builtin_amdgcn_mfma_f32_16x16x32_f16(afl[tm], bfh[tn], accx[tm][tn], 0, 0, 0);
            }
        __syncthreads();
        cur ^= 1;
    }
#undef STAGE_P
#pragma unroll
    for (int tm = 0; tm < 4; ++tm)
#pragma unroll
        for (int reg = 0; reg < 4; ++reg) {
            int m = m0 + wm * 64 + tm * 16 + quad * 4 + reg;
            if (m < M) {
#pragma unroll
                for (int tn = 0; tn < 4; ++tn) {
                    int n = n0 + wn * 64 + tn * 16 + l15;
                    u[(size_t)m * 1536 + n] = acch[tm][tn][reg] + accx[tm][tn][reg] * (1.0f / 4096.0f);
                }
            }
        }
}

// combine (s<=128): resid -= 0.5*h + 0.5*(conv+bias); h = lerp(embed[idx]),
// conv[t] = sum_tap lerp of u[.][tap] at t' = t+tap-1
__global__ __launch_bounds__(256) void k_combine(const float* __restrict__ u,
        const float* __restrict__ embed, const unsigned long long* __restrict__ minbuf,
        const float* __restrict__ bias, float* __restrict__ resid, int s, float scale) {
    int tid = threadIdx.x;
    int m = blockIdx.x * 2 + (tid >> 7);
    int d4 = (tid & 127) << 2;
    int b = m >> 9, t = m & 511;
    int bs = b * s;
    float4 bi = *(const float4*)(bias + d4);
    float uu = ((float)t + 0.5f) * scale - 0.5f;
    float fl = floorf(uu);
    float w = uu - fl;
    int i0 = (int)fl, i1 = i0 + 1;
    i0 = min(max(i0, 0), s - 1);
    i1 = min(max(i1, 0), s - 1);
    int c0 = (int)(unsigned)minbuf[bs + i0];
    int c1 = (int)(unsigned)minbuf[bs + i1];
    float4 e0 = *(const float4*)(embed + (size_t)c0 * 512 + d4);
    float4 e1 = *(const float4*)(embed + (size_t)c1 * 512 + d4);
    float om = 1.0f - w;
    float4 h4;
    h4.x = om * e0.x + w * e1.x; h4.y = om * e0.y + w * e1.y;
    h4.z = om * e0.z + w * e1.z; h4.w = om * e0.w + w * e1.w;
    float4 conv = make_float4(0.f, 0.f, 0.f, 0.f);
#pragma unroll
    for (int tap = 0; tap < 3; ++tap) {
        int tt = t + tap - 1;
        if (tt >= 0 && tt < 512) {
            float uu2 = ((float)tt + 0.5f) * scale - 0.5f;
            float fl2 = floorf(uu2);
            float w2 = uu2 - fl2;
            int j0 = (int)fl2, j1 = j0 + 1;
            j0 = min(max(j0, 0), s - 1);
            j1 = min(max(j1, 0), s - 1);
            float4 a4 = *(const float4*)(u + (size_t)(bs + j0) * 1536 + tap * 512 + d4);
            float4 b4 = *(const float4*)(u + (size_t)(bs + j1) * 1536 + tap * 512 + d4);
            float ow = 1.0f - w2;
            conv.x += ow * a4.x + w2 * b4.x;
            conv.y += ow * a4.y + w2 * b4.y;
            conv.z += ow * a4.z + w2 * b4.z;
            conv.w += ow * a4.w + w2 * b4.w;
        }
    }
    size_t off = (size_t)m * 512 + d4;
    float4 rv = *(float4*)(resid + off);
    rv.x -= 0.5f * h4.x + 0.5f * (conv.x + bi.x);
    rv.y -= 0.5f * h4.y + 0.5f * (conv.y + bi.y);
    rv.z -= 0.5f * h4.z + 0.5f * (conv.z + bi.z);
    rv.w -= 0.5f * h4.w + 0.5f * (conv.w + bi.w);
    *(float4*)(resid + off) = rv;
}

// direct conv (s in {256,512}): GEMM [8192 x 1536(tap,din)] x [1536 x 512(dout)]
// A rows = split(lerp of embed rows at t'=t+tap-1); B = Wt2 rows (tap*512+dout).
// epilogue: resid -= 0.5*h + 0.5*(conv+bias)
__global__ __launch_bounds__(256, 2) void k_conv(const _Float16* __restrict__ eh,
        const _Float16* __restrict__ el, const float* __restrict__ embed,
        const _Float16* __restrict__ wh, const _Float16* __restrict__ wl,
        const float* __restrict__ bias, const unsigned long long* __restrict__ minbuf,
        float* __restrict__ resid, int s, float scale) {
    __shared__ _Float16 Ah[128][40], Al[128][40], Bh[128][40], Bl[128][40];
    __shared__ int c0s[132], c1s[132];
    __shared__ float wws[132];
    int tid = threadIdx.x;
    int lane = tid & 63, wave = tid >> 6;
    int wm = wave >> 1, wn = wave & 1;
    int quad = lane >> 4, l15 = lane & 15;
    int m0 = blockIdx.x * 128, n0 = blockIdx.y * 128;
    int b = m0 >> 9, t0 = m0 & 511, bs = b * s;
    int noint = (s == 512);
    if (tid < 130) {
        int tt = t0 + tid - 1;
        if (tt >= 0 && tt < 512) {
            float uu = ((float)tt + 0.5f) * scale - 0.5f;
            float fl = floorf(uu);
            float w = uu - fl;
            int i0 = (int)fl, i1 = i0 + 1;
            i0 = min(max(i0, 0), s - 1);
            i1 = min(max(i1, 0), s - 1);
            c0s[tid] = (int)(unsigned)minbuf[bs + i0];
            c1s[tid] = (int)(unsigned)minbuf[bs + i1];
            wws[tid] = w;
        } else { c0s[tid] = -1; c1s[tid] = -1; wws[tid] = 0.f; }
    }
    floatx4 acch[4][4], accx[4][4];
#pragma unroll
    for (int i = 0; i < 4; ++i)
#pragma unroll
        for (int j = 0; j < 4; ++j)
#pragma unroll
            for (int r = 0; r < 4; ++r) { acch[i][j][r] = 0.f; accx[i][j][r] = 0.f; }
    __syncthreads();
    for (int kb = 0; kb < 1536; kb += 32) {
        int tap = kb >> 9, din0 = kb & 511;
#pragma unroll
        for (int r = 0; r < 2; ++r) {
            int c = tid + r * 256;
            int row = c >> 2, c8 = c & 3;
            int j = row + tap;
            int cc0 = c0s[j], cc1 = c1s[j];
            half8v hh8, ll8;
            if (cc0 < 0) {
                hh8 = (half8v)(_Float16)0.f;
                ll8 = (half8v)(_Float16)0.f;
                *(half8v*)&Ah[row][c8 * 8] = hh8;
                *(half8v*)&Al[row][c8 * 8] = ll8;
            } else if (noint) {
                *(int4*)&Ah[row][c8 * 8] = *(const int4*)(eh + (size_t)cc0 * 512 + din0 + c8 * 8);
                *(int4*)&Al[row][c8 * 8] = *(const int4*)(el + (size_t)cc0 * 512 + din0 + c8 * 8);
            } else {
                float w = wws[j], ow = 1.0f - w;
                const float* p0 = embed + (size_t)cc0 * 512 + din0 + c8 * 8;
                const float* p1 = embed + (size_t)cc1 * 512 + din0 + c8 * 8;
                float4 a0 = *(const float4*)p0, a1 = *(const float4*)(p0 + 4);
                float4 b0 = *(const float4*)p1, b1 = *(const float4*)(p1 + 4);
                float vals[8];
                vals[0] = ow * a0.x + w * b0.x; vals[1] = ow * a0.y + w * b0.y;
                vals[2] = ow * a0.z + w * b0.z; vals[3] = ow * a0.w + w * b0.w;
                vals[4] = ow * a1.x + w * b1.x; vals[5] = ow * a1.y + w * b1.y;
                vals[6] = ow * a1.z + w * b1.z; vals[7] = ow * a1.w + w * b1.w;
#pragma unroll
                for (int q = 0; q < 8; ++q) {
                    HL hl = split2(vals[q]);
                    hh8[q] = hl.h; ll8[q] = hl.l;
                }
                *(half8v*)&Ah[row][c8 * 8] = hh8;
                *(half8v*)&Al[row][c8 * 8] = ll8;
            }
            int brow = tap * 512 + n0 + row;     // Wt2 row = tap*512 + dout
            *(int4*)&Bh[row][c8 * 8] = *(const int4*)(wh + (size_t)brow * 512 + din0 + c8 * 8);
            *(int4*)&Bl[row][c8 * 8] = *(const int4*)(wl + (size_t)brow * 512 + din0 + c8 * 8);
        }
        __syncthreads();
        half8v afh[4], afl[4], bfh[4], bfl[4];
#pragma unroll
        for (int tm = 0; tm < 4; ++tm) {
            afh[tm] = *(const half8v*)&Ah[wm * 64 + tm * 16 + l15][quad * 8];
            afl[tm] = *(const half8v*)&Al[wm * 64 + tm * 16 + l15][quad * 8];
        }
#pragma unroll
        for (int tn = 0; tn < 4; ++tn) {
            bfh[tn] = *(const half8v*)&Bh[wn * 64 + tn * 16 + l15][quad * 8];
            bfl[tn] = *(const half8v*)&Bl[wn * 64 + tn * 16 + l15][quad * 8];
        }
#pragma unroll
        for (int tm = 0; tm < 4; ++tm)
#pragma unroll
            for (int tn = 0; tn < 4; ++tn) {
                acch[tm][tn] = __builtin_amdgcn_mfma_f32_16x16x32_f16(afh[tm], bfh[tn], acch[tm][tn], 0, 0, 0);
                accx[tm][tn] = __builtin_amdgcn_mfma_f32_16x16x32_f16(afh[tm], bfl[tn], accx[tm][tn], 0, 0, 0);
                accx[tm][tn] = __builtin_amdgcn_mfma_f32_16x16x32_f16(afl[tm], bfh[tn], accx[tm][tn], 0, 0, 0);
            }
        __syncthreads();
    }
#pragma unroll
    for (int tm = 0; tm < 4; ++tm)
#pragma unroll
        for (int reg = 0; reg < 4; ++reg) {
            int row = wm * 64 + tm * 16 + quad * 4 + reg;
            int m = m0 + row;
            int jj = row + 1;                  // tap=1 -> t'=t
            int cc0 = c0s[jj], cc1 = c1s[jj];
            float w = wws[jj], ow = 1.0f - w;
#pragma unroll
            for (int tn = 0; tn < 4; ++tn) {
                int n = n0 + wn * 64 + tn * 16 + l15;
                float h = ow * embed[(size_t)cc0 * 512 + n] + w * embed[(size_t)cc1 * 512 + n];
                float val = acch[tm][tn][reg] + accx[tm][tn][reg] * (1.0f / 4096.0f);
                size_t off = (size_t)m * 512 + n;
                resid[off] -= 0.5f * h + 0.5f * (val + bias[n]);
            }
        }
}

__global__ __launch_bounds__(256) void k_final(const float* __restrict__ x,
        const float* __restrict__ resid, float* __restrict__ out) {
    int gid = blockIdx.x * 256 + threadIdx.x;
    float4 xv = ((const float4*)x)[gid];
    float4 rv = ((const float4*)resid)[gid];
    float4 o;
    o.x = xv.x - rv.x; o.y = xv.y - rv.y; o.z = xv.z - rv.z; o.w = xv.w - rv.w;
    ((float4*)out)[gid] = o;
}

extern "C" void kernel_launch(void* const* d_in, const int* in_sizes, int n_in,
                              void* d_out, int out_size, void* d_ws, size_t ws_size,
                              hipStream_t stream) {
    const float* x     = (const float*)d_in[0];
    const float* embed = (const float*)d_in[1];
    const float* pw    = (const float*)d_in[2];
    const float* pb    = (const float*)d_in[3];
    float* out = (float*)d_out;

    // ws layout (floats), ~54.6 MB total:
    // resid 16MB | U 16MB (zh/zl halves; u<=12.6MB aliases after dist) |
    // ehi/elo 8MB | Wt2 hi/lo 12MB | esq | minbuf
    float* resid = (float*)d_ws;
    float* Ubase = resid + 4194304;
    _Float16* zh = (_Float16*)Ubase;
    _Float16* zl = zh + 4194304;
    float* u = Ubase;
    _Float16* ehi = (_Float16*)(Ubase + 4194304);
    _Float16* elo = ehi + 2097152;
    _Float16* whi = elo + 2097152;
    _Float16* wlo = whi + 3145728;
    float* esq = (float*)(wlo + 3145728);
    unsigned long long* minbuf = (unsigned long long*)(esq + 4096);

    k_esq<<<1024, 256, 0, stream>>>(embed, esq);
    k_split_embed<<<2048, 256, 0, stream>>>(embed, ehi, elo);
    k_split_w<<<12288, 256, 0, stream>>>(pw, whi, wlo);
    k_copy<<<4096, 256, 0, stream>>>(x, resid);

    const int SCv[10] = {1, 2, 4, 8, 16, 32, 64, 128, 256, 512};
    // PHI_IDX with float64-ulp tie-breaks at si=2 and si=7 (verified round 2)
    const int PIv[10] = {0, 0, 1, 1, 1, 2, 2, 3, 3, 3};
    for (int si = 0; si < 10; ++si) {
        int s = SCv[si];
        int M = 16 * s;
        int kp = PIv[si];
        int lg = __builtin_ctz((unsigned)s);
        float scale = (float)s / 512.0f;
        k_zmean<<<(M * 512) / 256, 256, 0, stream>>>(resid, zh, zl, s, lg);
        (void)hipMemsetAsync(minbuf, 0xFF, (size_t)M * 8, stream);
        k_dist_mfma<<<dim3((M + 127) / 128, 32), 256, 0, stream>>>(zh, zl, ehi, elo, esq, minbuf, M);
        if (s <= 128) {
            k_phi<<<dim3((M + 127) / 128, 12), 256, 0, stream>>>(ehi, elo,
                    whi + (size_t)kp * 1536 * 512, wlo + (size_t)kp * 1536 * 512, minbuf, u, M);
            k_combine<<<4096, 256, 0, stream>>>(u, embed, minbuf, pb + kp * 512, resid, s, scale);
        } else {
            k_conv<<<dim3(64, 4), 256, 0, stream>>>(ehi, elo, embed,
                    whi + (size_t)kp * 1536 * 512, wlo + (size_t)kp * 1536 * 512,
                    pb + kp * 512, minbuf, resid, s, scale);
        }
    }
    k_final<<<4096, 256, 0, stream>>>(x, resid, out);
}